// Round 8
// baseline (989.802 us; speedup 1.0000x reference)
//
#include <hip/hip_runtime.h>
#include <hip/hip_bf16.h>

// ============================================================================
// ViT encoder (patch embed + windowed block + global block) on gfx950.
// Round 8 (= round 7 with the pkbf bit-cast compile fix):
//   - flash: software-pipelined K/V staging (prefetch regs, loads in flight
//     during compute), packed bf16 cvt for P, deferred l-sum reduction
//   - mgemm: templated tiles; N=768 GEMMs use 64x64 tiles (768 blocks,
//     3 blocks/CU instead of 1.5)
//   - batched weight-transpose conversions (9 launches -> 2)
// ============================================================================

using u16 = unsigned short;
using u32 = unsigned int;
using short8  = __attribute__((ext_vector_type(8))) short;
using floatx4 = __attribute__((ext_vector_type(4))) float;

__device__ __forceinline__ float bfu2f(u16 u) { return __builtin_bit_cast(float, (u32)u << 16); }
__device__ __forceinline__ u16   f2bfu(float f) {
  u32 u = __builtin_bit_cast(u32, f);
  return (u16)((u + 0x7fffu + ((u >> 16) & 1u)) >> 16);   // RNE
}
__device__ __forceinline__ u32 pkbf(float a, float b) {    // packed RNE cvt
  union { __hip_bfloat162 h; u32 u; } c;
  c.h = __float22bfloat162_rn(float2{a, b});
  return c.u;
}
#define DIV14(x) (((x) * 4682) >> 16)   // exact floor(x/14) for 0<=x<256
#define WAIT_VM0()   __builtin_amdgcn_s_waitcnt(0x3f70)   // vmcnt(0)
#define WAIT_LGKM0() __builtin_amdgcn_s_waitcnt(0xc07f)   // lgkmcnt(0)

// async global->LDS, 16B per lane; LDS dest = wave-uniform base + lane*16
__device__ __forceinline__ void gld_lds16(const u16* g, u16* l) {
  __builtin_amdgcn_global_load_lds(
      (const __attribute__((address_space(1))) u32*)g,
      (__attribute__((address_space(3))) u32*)l, 16, 0, 0);
}

// ---------------------------------------------------------------------------
// dtype detector: FLAG=1 => bf16 tensors, FLAG=0 => fp32.
// ---------------------------------------------------------------------------
__global__ __launch_bounds__(256) void detect_k(const u16* __restrict__ x, int* __restrict__ flag)
{
  __shared__ int tot;
  if (threadIdx.x == 0) tot = 0;
  __syncthreads();
  int cnt = 0;
  for (int i = threadIdx.x; i < 4096; i += 256) {
    int e = (x[2 * i] >> 7) & 0xFF;
    cnt += (e >= 100 && e <= 134) ? 1 : 0;
  }
  atomicAdd(&tot, cnt);
  __syncthreads();
  if (threadIdx.x == 0) *flag = (tot >= 2458) ? 1 : 0;
}

// ---------------------------------------------------------------------------
// small-param conversion -> bf16 mirror
// ---------------------------------------------------------------------------
struct CvtEnt { const void* src; int n; int dstoff; };
struct CvtArgs { CvtEnt e[24]; int cnt; };

__global__ __launch_bounds__(256) void tobf_multi_k(CvtArgs a, u16* __restrict__ dst,
                                                    const int* __restrict__ flag)
{
  int gid = blockIdx.x * 256 + threadIdx.x;
  bool isbf = (*flag != 0);
  for (int t = 0; t < a.cnt; ++t)
    if (gid < a.e[t].n)
      dst[a.e[t].dstoff + gid] = isbf ? ((const u16*)a.e[t].src)[gid]
                                      : f2bfu(((const float*)a.e[t].src)[gid]);
}

__global__ __launch_bounds__(256) void tobf4_k(const void* __restrict__ src, u16* __restrict__ dst,
                                               int n4, const int* __restrict__ flag)
{
  int i = blockIdx.x * 256 + threadIdx.x;
  if (i >= n4) return;
  ushort4 o;
  if (*flag) o = ((const ushort4*)src)[i];
  else {
    float4 f = ((const float4*)src)[i];
    o.x = f2bfu(f.x); o.y = f2bfu(f.y); o.z = f2bfu(f.z); o.w = f2bfu(f.w);
  }
  ((ushort4*)dst)[i] = o;
}

// ---------------------------------------------------------------------------
// Batched weight convert+transpose: W[K][N] -> Wt[N][K] bf16, 64x64 LDS
// tiles, multiple matrices per launch (descriptor scan).
// ---------------------------------------------------------------------------
struct TEnt { const void* src; int dstoff; int K; int N; int t0; };
struct TArgs { TEnt e[5]; int cnt; };

__global__ __launch_bounds__(256) void tobfTb_k(TArgs a, u16* __restrict__ dstbase,
                                                const int* __restrict__ flag)
{
  __shared__ u16 t[64][65];
  int bid = blockIdx.x, ei = 0;
  for (int i = 0; i < a.cnt; ++i) if (bid >= a.e[i].t0) ei = i;
  const TEnt E = a.e[ei];
  const int tt = bid - E.t0, ntx = E.N >> 6;
  const int ty = tt / ntx, tx = tt - ty * ntx;
  const int n0 = tx * 64, k0 = ty * 64;
  const int r = threadIdx.x >> 2, c = (threadIdx.x & 3) * 16;
  if (*flag) {
    const u16* s = (const u16*)E.src + (size_t)(k0 + r) * E.N + n0 + c;
    union { uint4 v[2]; u16 e[16]; } u;
    u.v[0] = *(const uint4*)s; u.v[1] = *(const uint4*)(s + 8);
    #pragma unroll
    for (int j = 0; j < 16; ++j) t[c + j][r] = u.e[j];
  } else {
    const float* s = (const float*)E.src + (size_t)(k0 + r) * E.N + n0 + c;
    #pragma unroll
    for (int j = 0; j < 16; ++j) t[c + j][r] = f2bfu(s[j]);
  }
  __syncthreads();
  union { uint4 v[2]; u16 e[16]; } o;
  #pragma unroll
  for (int j = 0; j < 16; ++j) o.e[j] = t[r][c + j];
  u16* d = dstbase + E.dstoff + (size_t)(n0 + r) * E.K + k0 + c;
  *(uint4*)d = o.v[0]; *(uint4*)(d + 8) = o.v[1];
}

// ---------------------------------------------------------------------------
// im2col for the 16x16/stride-16 patch embed
// ---------------------------------------------------------------------------
__global__ __launch_bounds__(256) void im2col_k(const void* __restrict__ xv, u16* __restrict__ a,
                                                const int* __restrict__ flag)
{
  int t = blockIdx.x, tid = threadIdx.x;
  int py = t >> 6, px = t & 63;
  int ky = tid >> 4, kx = tid & 15;
  size_t src = (size_t)(py * 16 + ky) * 1024 + px * 16 + kx;
  u16 v0, v1, v2;
  if (*flag) {
    const u16* x = (const u16*)xv;
    v0 = x[src]; v1 = x[src + 1048576]; v2 = x[src + 2097152];
  } else {
    const float* x = (const float*)xv;
    v0 = f2bfu(x[src]); v1 = f2bfu(x[src + 1048576]); v2 = f2bfu(x[src + 2097152]);
  }
  size_t dst = (size_t)t * 768 + tid * 3;
  a[dst] = v0; a[dst + 1] = v1; a[dst + 2] = v2;
}

// ---------------------------------------------------------------------------
// LayerNorm over C=768, f32 in -> bf16 out
// ---------------------------------------------------------------------------
__global__ __launch_bounds__(256) void ln_k(const float* __restrict__ x,
                                            const u16* __restrict__ g,
                                            const u16* __restrict__ b,
                                            u16* __restrict__ y)
{
  const int t = blockIdx.x, tid = threadIdx.x;
  const float* xp = x + (size_t)t * 768;
  float v0 = xp[tid], v1 = xp[tid + 256], v2 = xp[tid + 512];
  float s = v0 + v1 + v2;
  float q = v0 * v0 + v1 * v1 + v2 * v2;
  #pragma unroll
  for (int off = 32; off; off >>= 1) { s += __shfl_xor(s, off); q += __shfl_xor(q, off); }
  __shared__ float red[8];
  int wid = tid >> 6, lane = tid & 63;
  if (lane == 0) { red[wid] = s; red[4 + wid] = q; }
  __syncthreads();
  s = red[0] + red[1] + red[2] + red[3];
  q = red[4] + red[5] + red[6] + red[7];
  float mean = s * (1.f / 768.f);
  float var  = q * (1.f / 768.f) - mean * mean;
  float rstd = rsqrtf(var + 1e-5f);
  u16* yp = y + (size_t)t * 768;
  yp[tid]       = f2bfu((v0 - mean) * rstd * bfu2f(g[tid])       + bfu2f(b[tid]));
  yp[tid + 256] = f2bfu((v1 - mean) * rstd * bfu2f(g[tid + 256]) + bfu2f(b[tid + 256]));
  yp[tid + 512] = f2bfu((v2 - mean) * rstd * bfu2f(g[tid + 512]) + bfu2f(b[tid + 512]));
}

// ---------------------------------------------------------------------------
// Window partition 64x64 -> 25 windows of 14x14 zero-padded
// ---------------------------------------------------------------------------
__global__ __launch_bounds__(256) void win_part_k(const u16* __restrict__ ln, u16* __restrict__ w)
{
  int vid = blockIdx.x * 256 + threadIdx.x;
  if (vid >= 470400) return;
  size_t idx = (size_t)vid * 8;
  int c = (int)(idx % 768);
  int r = (int)(idx / 768);
  int win = r / 196, tok = r - win * 196;
  int gy = (win / 5) * 14 + tok / 14;
  int gx = (win % 5) * 14 + tok % 14;
  uint4 v = make_uint4(0, 0, 0, 0);
  if (gy < 64 && gx < 64)
    v = *(const uint4*)(ln + ((size_t)(gy * 64 + gx) * 768 + c));
  *(uint4*)(w + idx) = v;
}

// ---------------------------------------------------------------------------
// MFMA GEMM, double-buffered global_load_lds staging, templated tiling.
// C = A(MxK) * Bt(NxK)^T + bias, fused epilogues. BMxBN tile, BK=32,
// 4 waves in NWM x NWN grid, wave tile (BM/NWM) x (BN/NWN).
// ---------------------------------------------------------------------------
enum { MODE_FEAT = 0, MODE_QKV = 1, MODE_RES = 2, MODE_GELU = 3, MODE_OUT = 4 };

template<int BM, int BN, int NWM, int NWN>
__global__ __launch_bounds__(256) void mgemm_k(
    const u16* __restrict__ A, const u16* __restrict__ Bt, const u16* __restrict__ bias,
    int M, int N, int K, int mode,
    float* __restrict__ outf, u16* __restrict__ outb,
    const float* __restrict__ res, const u16* __restrict__ pos,
    u16* __restrict__ qb, u16* __restrict__ kb, u16* __restrict__ vt, int TW,
    const int* __restrict__ flagp)
{
  constexpr int WTM = BM / NWM, WTN = BN / NWN;
  constexpr int MS = WTM / 16, NS = WTN / 16;
  constexpr int RA = BM / 4, RB = BN / 4;       // staging rows per wave
  __shared__ __align__(16) u16 As[2][BM * 32];
  __shared__ __align__(16) u16 Bs[2][BN * 32];
  const int tid = threadIdx.x;
  const int wid = tid >> 6, lane = tid & 63;
  const int l15 = lane & 15, quad = lane >> 4;
  const int wm = wid / NWN, wn = wid % NWN;
  const int m0 = blockIdx.y * BM, n0 = blockIdx.x * BN;

  floatx4 acc[MS][NS];
  #pragma unroll
  for (int i = 0; i < MS; ++i)
    #pragma unroll
    for (int j = 0; j < NS; ++j) acc[i][j] = (floatx4){0.f, 0.f, 0.f, 0.f};

  const int sr = lane >> 2, sc = (lane & 3) * 8;
  const u16* ag[RA / 16];
  const u16* bg[RB / 16];
  #pragma unroll
  for (int i = 0; i < RA / 16; ++i)
    ag[i] = A + (size_t)min(m0 + wid * RA + i * 16 + sr, M - 1) * K + sc;
  #pragma unroll
  for (int i = 0; i < RB / 16; ++i)
    bg[i] = Bt + (size_t)(n0 + wid * RB + i * 16 + sr) * K + sc;

  auto issue = [&](int buf, int k0) {
    #pragma unroll
    for (int i = 0; i < RA / 16; ++i)
      gld_lds16(ag[i] + k0, &As[buf][(wid * RA + i * 16) * 32]);
    #pragma unroll
    for (int i = 0; i < RB / 16; ++i)
      gld_lds16(bg[i] + k0, &Bs[buf][(wid * RB + i * 16) * 32]);
  };

  issue(0, 0);
  int bufi = 0;
  for (int k0 = 0; k0 < K; k0 += 32, bufi ^= 1) {
    WAIT_VM0();
    __syncthreads();
    if (k0 + 32 < K) issue(bufi ^ 1, k0 + 32);
    short8 af[MS], bf[NS];
    #pragma unroll
    for (int ms = 0; ms < MS; ++ms)
      af[ms] = *(const short8*)&As[bufi][(wm * WTM + ms * 16 + l15) * 32 + quad * 8];
    #pragma unroll
    for (int ns = 0; ns < NS; ++ns)
      bf[ns] = *(const short8*)&Bs[bufi][(wn * WTN + ns * 16 + l15) * 32 + quad * 8];
    #pragma unroll
    for (int ms = 0; ms < MS; ++ms)
      #pragma unroll
      for (int ns = 0; ns < NS; ++ns)
        acc[ms][ns] = __builtin_amdgcn_mfma_f32_16x16x32_bf16(af[ms], bf[ns], acc[ms][ns], 0, 0, 0);
  }

  const bool outbf = (mode == MODE_OUT) ? (*flagp != 0) : false;
  #pragma unroll
  for (int ms = 0; ms < MS; ++ms) {
    const int gmb = m0 + wm * WTM + ms * 16 + quad * 4;
    #pragma unroll
    for (int ns = 0; ns < NS; ++ns) {
      const int gn = n0 + wn * WTN + ns * 16 + l15;
      const float bb = bfu2f(bias[gn]);
      if (mode == MODE_QKV) {
        const int s = gn / 768, nn = gn - s * 768, h = nn >> 6, d = nn & 63;
        #pragma unroll
        for (int r = 0; r < 4; ++r) {
          int gm = gmb + r; if (gm >= M) continue;
          float v = acc[ms][ns][r] + bb;
          int b = gm / TW, tok = gm - b * TW;
          size_t bh = (size_t)(b * 12 + h);
          if (s == 0)      qb[(bh * TW + tok) * 64 + d] = f2bfu(v);
          else if (s == 1) kb[(bh * TW + tok) * 64 + d] = f2bfu(v);
          else             vt[(bh * 64 + d) * TW + tok] = f2bfu(v);
        }
      } else {
        #pragma unroll
        for (int r = 0; r < 4; ++r) {
          int gm = gmb + r; if (gm >= M) continue;
          size_t o = (size_t)gm * N + gn;
          float v = acc[ms][ns][r] + bb;
          if (mode == MODE_FEAT)      outf[o] = v + bfu2f(pos[o]);
          else if (mode == MODE_RES)  outf[o] = v + res[o];
          else if (mode == MODE_GELU) outb[o] = f2bfu(0.5f * v * (1.f + erff(v * 0.70710678f)));
          else {
            float ov = v + res[o];
            if (outbf) outb[o] = f2bfu(ov);
            else       outf[o] = ov;
          }
        }
      }
    }
  }
}

// ---------------------------------------------------------------------------
// MFMA flash attention, software-pipelined K/V staging.
// LDS: RQ (Q stage -> P), RK (K tile; !WIN GW scratch pre-loop), RV (V tile;
// rel staging pre-loop), RG (GH; +GW for WIN). Q fragment in VGPRs.
// Global block: Gh folded into softmax shift; Gw hoisted to registers.
// l-sum kept as per-lane partials; one 16-lane reduction after the loop.
// ---------------------------------------------------------------------------
template<int NT, int TD, bool WIN>
__global__ __launch_bounds__(256) void flash_k(
    const u16* __restrict__ qb, const u16* __restrict__ kb, const u16* __restrict__ vt,
    const u16* __restrict__ relh, const u16* __restrict__ relw,
    u16* __restrict__ outb)
{
  constexpr int NTAB = 2 * TD - 1;
  constexpr int KT = (NT + 63) >> 6;
  constexpr int TS = 72;
  constexpr int RQ = 0;               // Q stage, then P
  constexpr int RK = 64 * TS;         // K tile; !WIN: GW scratch (stride 66)
  constexpr int RV = 2 * 64 * TS;     // V tile; rel-table staging pre-loop
  constexpr int RG = 3 * 64 * TS;     // GH
  constexpr int GHS = WIN ? 34 : 66;
  constexpr int GWWIN = RG + 64 * GHS;
  constexpr int TOT = WIN ? (GWWIN + 64 * 34) : (RG + 64 * GHS);
  __shared__ __align__(16) u16 lds[TOT];

  const int tid = threadIdx.x, wid = tid >> 6, lane = tid & 63;
  const int l15 = lane & 15, quad = lane >> 4;
  const int qt = blockIdx.x, bh = blockIdx.y;
  const int q0 = qt * 64;
  const size_t kvbase = (size_t)bh * NT * 64;
  const size_t vbase  = (size_t)bh * 64 * NT;

  // ---- K/V prefetch registers ----
  uint4 pK0, pK1, pV0, pV1;
  u16 pVs[16];
  const int str = tid >> 2, stc = (tid & 3) << 4;
  auto loadK = [&](int kt) {
    const int key = min(kt * 64 + str, NT - 1);
    const uint4* p = (const uint4*)(kb + kvbase + (size_t)key * 64 + stc);
    pK0 = p[0]; pK1 = p[1];
  };
  auto loadV = [&](int kt) {
    if constexpr (NT % 64 == 0) {
      const uint4* p = (const uint4*)(vt + vbase + (size_t)str * NT + kt * 64 + stc);
      pV0 = p[0]; pV1 = p[1];
    } else {
      #pragma unroll
      for (int j = 0; j < 16; ++j) {
        int key = min(kt * 64 + stc + j, NT - 1);
        pVs[j] = vt[vbase + (size_t)str * NT + key];
      }
    }
  };
  loadK(0); loadV(0);   // in flight across the whole G phase

  // ---- stage Q tile, hoist fragment to VGPRs ----
  {
    const int tok = min(q0 + str, NT - 1);
    const uint4* p = (const uint4*)(qb + kvbase + (size_t)tok * 64 + stc);
    *(uint4*)&lds[RQ + str * TS + stc]     = p[0];
    *(uint4*)&lds[RQ + str * TS + stc + 8] = p[1];
  }
  __syncthreads();
  short8 qf[2];
  qf[0] = *(const short8*)&lds[RQ + (wid * 16 + l15) * TS + quad * 8];
  qf[1] = *(const short8*)&lds[RQ + (wid * 16 + l15) * TS + 32 + quad * 8];
  WAIT_LGKM0();   // Q reads done before P writes touch RQ

  auto stageRB = [&](const u16* tab, int rowoff, int maxrow) {
    const int tr = min(rowoff + str, maxrow);
    const uint4* p = (const uint4*)(tab + (size_t)tr * 64 + stc);
    *(uint4*)&lds[RV + str * TS + stc]     = p[0];
    *(uint4*)&lds[RV + str * TS + stc + 8] = p[1];
  };
  auto gpass = [&](int gbase, int gstride, int ncols) {
    for (int ns = 0; ns < ncols / 16; ++ns) {
      floatx4 g = (floatx4){0.f, 0.f, 0.f, 0.f};
      #pragma unroll
      for (int ks = 0; ks < 2; ++ks) {
        short8 b = *(const short8*)&lds[RV + (ns * 16 + l15) * TS + ks * 32 + quad * 8];
        g = __builtin_amdgcn_mfma_f32_16x16x32_bf16(qf[ks], b, g, 0, 0, 0);
      }
      u32 g01 = pkbf(g[0], g[1]), g23 = pkbf(g[2], g[3]);
      u16* gp = &lds[gbase + (wid * 16 + quad * 4) * gstride + ns * 16 + l15];
      gp[0] = (u16)g01; gp[gstride] = (u16)(g01 >> 16);
      gp[2 * gstride] = (u16)g23; gp[3 * gstride] = (u16)(g23 >> 16);
    }
  };

  float gwv[4][4];
  if constexpr (!WIN) {
    stageRB(relh, qt, NTAB - 1);  __syncthreads();
    gpass(RG, GHS, 64);                           // GH (wave-private rows)
    __syncthreads();
    stageRB(relw, 0, NTAB - 1);   __syncthreads();
    gpass(RK, 66, 64);                            // GW cols 0..63
    #pragma unroll
    for (int r = 0; r < 4; ++r) {
      const int tr = wid * 16 + quad * 4 + r;
      #pragma unroll
      for (int ns = 0; ns < 4; ++ns) {
        const int iw = tr - (ns * 16 + l15) + 63;
        if (iw < 64) gwv[ns][r] = bfu2f(lds[RK + tr * 66 + iw]);
      }
    }
    WAIT_LGKM0();
    __syncthreads();
    stageRB(relw, 64, NTAB - 1);  __syncthreads();
    gpass(RK, 66, 64);                            // GW cols 64..127
    #pragma unroll
    for (int r = 0; r < 4; ++r) {
      const int tr = wid * 16 + quad * 4 + r;
      #pragma unroll
      for (int ns = 0; ns < 4; ++ns) {
        const int iw = tr - (ns * 16 + l15) + 63;
        if (iw >= 64) gwv[ns][r] = bfu2f(lds[RK + tr * 66 + iw - 64]);
      }
    }
    WAIT_LGKM0();   // GW reads done before k-loop restages RK
  } else {
    stageRB(relh, 0, NTAB - 1);  __syncthreads();
    gpass(RG, 34, 32);
    __syncthreads();
    stageRB(relw, 0, NTAB - 1);  __syncthreads();
    gpass(GWWIN, 34, 32);
  }

  // ---- online-softmax state ----
  float mI[4], sL[4];
  floatx4 Oacc[4];
  #pragma unroll
  for (int r = 0; r < 4; ++r) { mI[r] = -3e38f; sL[r] = 0.f; }
  #pragma unroll
  for (int d = 0; d < 4; ++d) Oacc[d] = (floatx4){0.f, 0.f, 0.f, 0.f};

  // ---- K loop (pipelined) ----
  for (int kt = 0; kt < KT; ++kt) {
    __syncthreads();            // prior tile's LDS reads done before restage
    *(uint4*)&lds[RK + str * TS + stc]     = pK0;
    *(uint4*)&lds[RK + str * TS + stc + 8] = pK1;
    if constexpr (NT % 64 == 0) {
      *(uint4*)&lds[RV + str * TS + stc]     = pV0;
      *(uint4*)&lds[RV + str * TS + stc + 8] = pV1;
    } else {
      #pragma unroll
      for (int j = 0; j < 16; ++j) lds[RV + str * TS + stc + j] = pVs[j];
    }
    __syncthreads();
    if (kt + 1 < KT) { loadK(kt + 1); loadV(kt + 1); }   // fly during compute

    // QK^T (A = hoisted Q regs)
    floatx4 sacc[4];
    #pragma unroll
    for (int ns = 0; ns < 4; ++ns) sacc[ns] = (floatx4){0.f, 0.f, 0.f, 0.f};
    #pragma unroll
    for (int ks = 0; ks < 2; ++ks)
      #pragma unroll
      for (int ns = 0; ns < 4; ++ns) {
        short8 b = *(const short8*)&lds[RK + (ns * 16 + l15) * TS + ks * 32 + quad * 8];
        sacc[ns] = __builtin_amdgcn_mfma_f32_16x16x32_bf16(qf[ks], b, sacc[ns], 0, 0, 0);
      }

    // scale + rel bias
    float sv[4][4];
    #pragma unroll
    for (int r = 0; r < 4; ++r) {
      if constexpr (!WIN) {
        #pragma unroll
        for (int ns = 0; ns < 4; ++ns)
          sv[ns][r] = fmaf(0.125f, sacc[ns][r], gwv[ns][r]);   // Gh folded below
      } else {
        const int tr = wid * 16 + quad * 4 + r;
        const int tok = q0 + tr;
        const int qy = DIV14(tok), qx = tok - 14 * qy;
        #pragma unroll
        for (int ns = 0; ns < 4; ++ns) {
          const int j = kt * 64 + ns * 16 + l15;
          const int ky = DIV14(j), kx = j - 14 * ky;
          int ih = qy - ky + 13; ih = max(0, min(ih, 31));
          int iw = qx - kx + 13; iw = max(0, min(iw, 31));
          float s = 0.125f * sacc[ns][r] + bfu2f(lds[RG + tr * 34 + ih])
                                        + bfu2f(lds[GWWIN + tr * 34 + iw]);
          sv[ns][r] = (j < NT) ? s : -1e30f;
        }
      }
    }

    // online softmax (row lives across 16 lanes of a quad); deferred l-sum
    #pragma unroll
    for (int r = 0; r < 4; ++r) {
      const int tr = wid * 16 + quad * 4 + r;
      float rm = fmaxf(fmaxf(sv[0][r], sv[1][r]), fmaxf(sv[2][r], sv[3][r]));
      #pragma unroll
      for (int off = 1; off < 16; off <<= 1) rm = fmaxf(rm, __shfl_xor(rm, off));
      float ghv = 0.f;
      if constexpr (!WIN) ghv = bfu2f(lds[RG + tr * GHS + (63 - kt)]);   // tile-const
      const float mt = rm + ghv;
      const float mn = fmaxf(mI[r], mt);
      const float al = __expf(mI[r] - mn);
      mI[r] = mn;
      const float tshift = mn - ghv;
      const float p0 = __expf(sv[0][r] - tshift);
      const float p1 = __expf(sv[1][r] - tshift);
      const float p2 = __expf(sv[2][r] - tshift);
      const float p3 = __expf(sv[3][r] - tshift);
      sL[r] = sL[r] * al + (p0 + p1 + p2 + p3);
      const u32 q01 = pkbf(p0, p1), q23 = pkbf(p2, p3);
      u16* pp = &lds[RQ + tr * TS + l15];
      pp[0]  = (u16)q01; pp[16] = (u16)(q01 >> 16);
      pp[32] = (u16)q23; pp[48] = (u16)(q23 >> 16);
      #pragma unroll
      for (int d = 0; d < 4; ++d) Oacc[d][r] *= al;
    }

    // PV
    #pragma unroll
    for (int ks = 0; ks < 2; ++ks) {
      short8 a = *(const short8*)&lds[RQ + (wid * 16 + l15) * TS + ks * 32 + quad * 8];
      #pragma unroll
      for (int d = 0; d < 4; ++d) {
        short8 b = *(const short8*)&lds[RV + (d * 16 + l15) * TS + ks * 32 + quad * 8];
        Oacc[d] = __builtin_amdgcn_mfma_f32_16x16x32_bf16(a, b, Oacc[d], 0, 0, 0);
      }
    }
  }

  // ---- final l-sum reduction + output ----
  #pragma unroll
  for (int r = 0; r < 4; ++r) {
    float s = sL[r];
    #pragma unroll
    for (int off = 1; off < 16; off <<= 1) s += __shfl_xor(s, off);
    const float rinv = 1.f / s;
    const int tr = wid * 16 + quad * 4 + r;
    const int tok = q0 + tr;
    if constexpr (WIN) {
      if (tok >= NT) continue;
      const int win = bh / 12, h = bh - win * 12;
      const int ty = DIV14(tok), tx = tok - 14 * ty;
      const int gy = (win / 5) * 14 + ty, gx = (win % 5) * 14 + tx;
      if (gy >= 64 || gx >= 64) continue;
      u16* op = outb + (size_t)(gy * 64 + gx) * 768 + h * 64;
      #pragma unroll
      for (int d = 0; d < 4; ++d) op[d * 16 + l15] = f2bfu(Oacc[d][r] * rinv);
    } else {
      u16* op = outb + (size_t)tok * 768 + bh * 64;
      #pragma unroll
      for (int d = 0; d < 4; ++d) op[d * 16 + l15] = f2bfu(Oacc[d][r] * rinv);
    }
  }
}

// ---------------------------------------------------------------------------
extern "C" void kernel_launch(void* const* d_in, const int* in_sizes, int n_in,
                              void* d_out, int out_size, void* d_ws, size_t ws_size,
                              hipStream_t stream)
{
  const void* x      = d_in[0];
  const void* patchw = d_in[1];
  const void* patchb = d_in[2];
  const void* pos    = d_in[3];
  const void *ln1g1 = d_in[4],  *ln1b1 = d_in[5];
  const void *qkvw1 = d_in[6],  *qkvb1 = d_in[7];
  const void *projw1= d_in[8],  *projb1= d_in[9];
  const void *relh1 = d_in[10], *relw1 = d_in[11];
  const void *ln2g1 = d_in[12], *ln2b1 = d_in[13];
  const void *mw11  = d_in[14], *mb11  = d_in[15];
  const void *mw21  = d_in[16], *mb21  = d_in[17];
  const void *ln1g2 = d_in[18], *ln1b2 = d_in[19];
  const void *qkvw2 = d_in[20], *qkvb2 = d_in[21];
  const void *projw2= d_in[22], *projb2= d_in[23];
  const void *relh2 = d_in[24], *relw2 = d_in[25];
  const void *ln2g2 = d_in[26], *ln2b2 = d_in[27];
  const void *mw12  = d_in[28], *mb12  = d_in[29];
  const void *mw22  = d_in[30], *mb22  = d_in[31];

  char* w = (char*)d_ws;
  int*   FLAG = (int*)w;  w += 64;
  float* R0 = (float*)w;  w += 12582912;
  float* R1 = (float*)w;  w += 12582912;
  u16*   B0 = (u16*)w;    w += 6291456;
  u16*   Wb = (u16*)w;    w += 7526400;
  u16*   QB = (u16*)w;    w += 7526400;   // [bh][tok][64]
  u16*   KB = (u16*)w;    w += 7526400;   // [bh][tok][64]
  u16*   VT = (u16*)w;    w += 7526400;   // [bh][d][tok]
  u16*   Hb = (u16*)w;    w += 25165824;
  u16*   WA = (u16*)w;    w += 15335424;  // transposed weight arena (+patch slot)
  u16*   POSb = (u16*)w;  w += 6291456;
  u16*   PRM = (u16*)w;   w += 106560;
  u16*   Ap = Hb;

  // weight-arena element offsets
  constexpr int WA_PATCH = 0, WA_QKV = 589824, WA_PROJ = 2359296,
                WA_M1 = 2949120, WA_M2 = 5308416;
  constexpr int PRM_PATCHB = 0, PB1 = 768, PBLK = 26240, PB2 = 768 + PBLK;
  constexpr int O_QKVB = 0, O_PROJB = 2304, O_MB1 = 3072, O_MB2 = 6144,
                O_LN1G = 6912, O_LN1B = 7680, O_LN2G = 8448, O_LN2B = 9216,
                O_RELH = 9984, O_RELW = 18112;

  detect_k<<<1, 256, 0, stream>>>((const u16*)x, FLAG);
  CvtArgs ca; int kk = 0;
  auto add = [&](const void* s, int n, int off) { ca.e[kk].src = s; ca.e[kk].n = n; ca.e[kk].dstoff = off; ++kk; };
  add(patchb, 768, PRM_PATCHB);
  add(qkvb1, 2304, PB1 + O_QKVB); add(projb1, 768, PB1 + O_PROJB);
  add(mb11, 3072, PB1 + O_MB1);   add(mb21, 768, PB1 + O_MB2);
  add(ln1g1, 768, PB1 + O_LN1G);  add(ln1b1, 768, PB1 + O_LN1B);
  add(ln2g1, 768, PB1 + O_LN2G);  add(ln2b1, 768, PB1 + O_LN2B);
  add(relh1, 27 * 64, PB1 + O_RELH); add(relw1, 27 * 64, PB1 + O_RELW);
  add(qkvb2, 2304, PB2 + O_QKVB); add(projb2, 768, PB2 + O_PROJB);
  add(mb12, 3072, PB2 + O_MB1);   add(mb22, 768, PB2 + O_MB2);
  add(ln1g2, 768, PB2 + O_LN1G);  add(ln1b2, 768, PB2 + O_LN1B);
  add(ln2g2, 768, PB2 + O_LN2G);  add(ln2b2, 768, PB2 + O_LN2B);
  add(relh2, 127 * 64, PB2 + O_RELH); add(relw2, 127 * 64, PB2 + O_RELW);
  ca.cnt = kk;
  tobf_multi_k<<<32, 256, 0, stream>>>(ca, PRM, FLAG);
  tobf4_k<<<3072, 256, 0, stream>>>(pos, POSb, 786432, FLAG);

  // ---- batch 1 weight conversions (patch + block 1, 1872 tiles) ----
  {
    TArgs ta;
    ta.e[0] = {patchw, WA_PATCH, 768, 768, 0};      // 144 tiles
    ta.e[1] = {qkvw1,  WA_QKV,   768, 2304, 144};   // 432
    ta.e[2] = {projw1, WA_PROJ,  768, 768, 576};    // 144
    ta.e[3] = {mw11,   WA_M1,    768, 3072, 720};   // 576
    ta.e[4] = {mw21,   WA_M2,   3072, 768, 1296};   // 576
    ta.cnt = 5;
    tobfTb_k<<<1872, 256, 0, stream>>>(ta, WA, FLAG);
  }

  // ---- patch embed ----
  im2col_k<<<4096, 256, 0, stream>>>(x, Ap, FLAG);
  mgemm_k<64, 64, 2, 2><<<dim3(12, 64), 256, 0, stream>>>(Ap, WA + WA_PATCH, PRM + PRM_PATCHB,
      4096, 768, 768, MODE_FEAT, R0, nullptr, nullptr, POSb, nullptr, nullptr, nullptr, 0, FLAG);

  // ---- block 1 (windowed) ----
  ln_k<<<4096, 256, 0, stream>>>(R0, PRM + PB1 + O_LN1G, PRM + PB1 + O_LN1B, B0);
  win_part_k<<<1838, 256, 0, stream>>>(B0, Wb);
  mgemm_k<128, 128, 2, 2><<<dim3(18, 39), 256, 0, stream>>>(Wb, WA + WA_QKV, PRM + PB1 + O_QKVB,
      4900, 2304, 768, MODE_QKV, nullptr, nullptr, nullptr, nullptr, QB, KB, VT, 196, FLAG);
  flash_k<196, 14, true><<<dim3(4, 300), 256, 0, stream>>>(QB, KB, VT,
      PRM + PB1 + O_RELH, PRM + PB1 + O_RELW, B0);
  mgemm_k<64, 64, 2, 2><<<dim3(12, 64), 256, 0, stream>>>(B0, WA + WA_PROJ, PRM + PB1 + O_PROJB,
      4096, 768, 768, MODE_RES, R1, nullptr, R0, nullptr, nullptr, nullptr, nullptr, 0, FLAG);
  ln_k<<<4096, 256, 0, stream>>>(R1, PRM + PB1 + O_LN2G, PRM + PB1 + O_LN2B, B0);
  mgemm_k<128, 128, 2, 2><<<dim3(24, 32), 256, 0, stream>>>(B0, WA + WA_M1, PRM + PB1 + O_MB1,
      4096, 3072, 768, MODE_GELU, nullptr, Hb, nullptr, nullptr, nullptr, nullptr, nullptr, 0, FLAG);
  mgemm_k<64, 64, 2, 2><<<dim3(12, 64), 256, 0, stream>>>(Hb, WA + WA_M2, PRM + PB1 + O_MB2,
      4096, 768, 3072, MODE_RES, R0, nullptr, R1, nullptr, nullptr, nullptr, nullptr, 0, FLAG);

  // ---- batch 2 weight conversions (block 2, 1728 tiles) ----
  {
    TArgs ta;
    ta.e[0] = {qkvw2,  WA_QKV,  768, 2304, 0};      // 432
    ta.e[1] = {projw2, WA_PROJ, 768, 768, 432};     // 144
    ta.e[2] = {mw12,   WA_M1,   768, 3072, 576};    // 576
    ta.e[3] = {mw22,   WA_M2,  3072, 768, 1152};    // 576
    ta.cnt = 4;
    tobfTb_k<<<1728, 256, 0, stream>>>(ta, WA, FLAG);
  }

  // ---- block 2 (global) ----
  ln_k<<<4096, 256, 0, stream>>>(R0, PRM + PB2 + O_LN1G, PRM + PB2 + O_LN1B, B0);
  mgemm_k<128, 128, 2, 2><<<dim3(18, 32), 256, 0, stream>>>(B0, WA + WA_QKV, PRM + PB2 + O_QKVB,
      4096, 2304, 768, MODE_QKV, nullptr, nullptr, nullptr, nullptr, QB, KB, VT, 4096, FLAG);
  flash_k<4096, 64, false><<<dim3(64, 12), 256, 0, stream>>>(QB, KB, VT,
      PRM + PB2 + O_RELH, PRM + PB2 + O_RELW, B0);
  mgemm_k<64, 64, 2, 2><<<dim3(12, 64), 256, 0, stream>>>(B0, WA + WA_PROJ, PRM + PB2 + O_PROJB,
      4096, 768, 768, MODE_RES, R1, nullptr, R0, nullptr, nullptr, nullptr, nullptr, 0, FLAG);
  ln_k<<<4096, 256, 0, stream>>>(R1, PRM + PB2 + O_LN2G, PRM + PB2 + O_LN2B, B0);
  mgemm_k<128, 128, 2, 2><<<dim3(24, 32), 256, 0, stream>>>(B0, WA + WA_M1, PRM + PB2 + O_MB1,
      4096, 3072, 768, MODE_GELU, nullptr, Hb, nullptr, nullptr, nullptr, nullptr, nullptr, 0, FLAG);
  mgemm_k<64, 64, 2, 2><<<dim3(12, 64), 256, 0, stream>>>(Hb, WA + WA_M2, PRM + PB2 + O_MB2,
      4096, 768, 3072, MODE_OUT, (float*)d_out, (u16*)d_out, R1, nullptr, nullptr, nullptr, nullptr, 0, FLAG);
}